// Round 12
// baseline (849.855 us; speedup 1.0000x reference)
//
#include <hip/hip_runtime.h>
#include <hip/hip_bf16.h>

// Problem constants
#define BATCH 4
#define S_TOT 4096
#define ROWS (BATCH * S_TOT)   // 16384
#define DM 2048
#define DSP 128
#define NSEG 512               // neurons per segment; 3 segments

typedef short short8 __attribute__((ext_vector_type(8)));
typedef float f32x16 __attribute__((ext_vector_type(16)));

// float -> bf16(RNE) bits; also returns the fp32 value of the bf16 for residual
static __device__ inline short f2bf(float v, float& back) {
  unsigned u = __float_as_uint(v);
  unsigned r = u + 0x7FFFu + ((u >> 16) & 1u);
  unsigned short hs = (unsigned short)(r >> 16);
  back = __uint_as_float(((unsigned)hs) << 16);
  return (short)hs;
}

// packed f32x2 -> bf16x2 (hw instr). Lo term is exact residual of hi's value.
static __device__ inline unsigned cvtpk2(float a, float b) {
  unsigned r;
  asm("v_cvt_pk_bf16_f32 %0, %1, %2" : "=v"(r) : "v"(a), "v"(b));
  return r;
}
static __device__ inline void cvt8(const float* v, short8& hi8, short8& lo8) {
  union { short8 s; unsigned u[4]; } H, L;
  #pragma unroll
  for (int w = 0; w < 4; ++w) {
    const float f0 = v[2 * w], f1 = v[2 * w + 1];
    const unsigned u = cvtpk2(f0, f1);
    const float b0 = __uint_as_float(u << 16);
    const float b1 = __uint_as_float(u & 0xffff0000u);
    L.u[w] = cvtpk2(f0 - b0, f1 - b1);
    H.u[w] = u;
  }
  hi8 = H.s; lo8 = L.s;
}

// global_load_lds, 16B per lane: per-lane global src, wave-uniform LDS dst
#define GLL16(gsrc, ldst)                                                       \
  __builtin_amdgcn_global_load_lds(                                             \
      (const __attribute__((address_space(1))) void*)(gsrc),                    \
      (__attribute__((address_space(3))) void*)(ldst), 16, 0, 0)

#define SBAR   __builtin_amdgcn_s_barrier()
#define SCHEDB __builtin_amdgcn_sched_barrier(0)

// ---------------- K0 fused: W-split pack (blocks 0..511) + emb norm pack -------
__global__ __launch_bounds__(64) void k0_prep(const float* __restrict__ W,
                                              const float* __restrict__ emb,
                                              short* __restrict__ wHi,
                                              short* __restrict__ wLo,
                                              short* __restrict__ eHi,
                                              short* __restrict__ eLo) {
  const int l = threadIdx.x;
  if (blockIdx.x < 512) {
    const int tc = blockIdx.x;
    const int t = tc >> 7, c = tc & 127;
    const int n = t * 32 + (l & 31);
    const int k = c * 16 + (l >> 5) * 8;
    const float4 a0 = *(const float4*)&W[(size_t)n * DM + k];
    const float4 a1 = *(const float4*)&W[(size_t)n * DM + k + 4];
    const float av[8] = {a0.x, a0.y, a0.z, a0.w, a1.x, a1.y, a1.z, a1.w};
    short8 hi8, lo8; float bk;
    #pragma unroll
    for (int e = 0; e < 8; ++e) {
      hi8[e] = f2bf(av[e], bk); lo8[e] = f2bf(av[e] - bk, bk);
    }
    const size_t idx = (size_t)tc * 64 + l;
    ((short8*)wHi)[idx] = hi8;
    ((short8*)wLo)[idx] = lo8;
  } else {
    const int row = blockIdx.x - 512;          // 0..1535
    __shared__ short sh[128], sl[128];
    float2 v = *(const float2*)&emb[row * 128 + l * 2];
    float ss = v.x * v.x + v.y * v.y;
    #pragma unroll
    for (int m = 32; m; m >>= 1) ss += __shfl_xor(ss, m);
    const float inv = 1.0f / fmaxf(sqrtf(ss), 1e-12f);
    float bk;
    const float ox = v.x * inv, oy = v.y * inv;
    sh[2 * l] = f2bf(ox, bk);     sl[2 * l] = f2bf(ox - bk, bk);
    sh[2 * l + 1] = f2bf(oy, bk); sl[2 * l + 1] = f2bf(oy - bk, bk);
    __syncthreads();
    if (l < 32) {
      const int split = l >> 4, kc = (l >> 1) & 7, kh = l & 1;
      const short* src = (split ? sl : sh) + kc * 16 + kh * 8;
      const short8 val = *(const short8*)src;
      const size_t idx = (size_t)(row >> 5) * 4096 + kc * 512 +
                         ((row & 31) + 32 * kh) * 8;
      *(short8*)((split ? eLo : eHi) + idx) = val;
    }
  }
}

// ---------------- K1 (templated): R8 counted-vmcnt structure + ablation modes --
// MODE 0: full; 1: A-path only (no B); 2: B+MFMA only (no A); 3: A-stream only.
// REP: internal repeat (diagnostics use 8 to clear the 75us fill dispatches).
#define NSTEP 32
template <int MODE, int REP>
__global__ __launch_bounds__(512, 2) void k1_diag(const float* __restrict__ x,
                                                  const short* __restrict__ wHi,
                                                  const short* __restrict__ wLo,
                                                  float* __restrict__ hPart) {
  constexpr bool useA = (MODE != 2);
  constexpr bool useB = (MODE == 0) || (MODE == 2);
  constexpr bool doMM = (MODE != 3);
  __shared__ __align__(16) char lbuf[2][32768];   // per buf: A 16KB | B 16KB
  const int t = threadIdx.x;
  const int wave = t >> 6, lane = t & 63;
  const int fr = lane & 31, ks = lane >> 5;
  const int rg = wave >> 1, cg = wave & 1;
  const int m0 = blockIdx.x * 128;
  const int y  = blockIdx.y;

  const int ar0 = wave * 16 + (lane >> 3);
  const int ar1 = ar0 + 8;
  const float* asrc0 = x + (size_t)(m0 + ar0) * DM + y * 1024 +
                       (((lane & 7) ^ (ar0 & 7)) << 2);
  const float* asrc1 = x + (size_t)(m0 + ar1) * DM + y * 1024 +
                       (((lane & 7) ^ (ar1 & 7)) << 2);
  const int c0 = wave * 2, c1 = wave * 2 + 1;
  const short* bsrc0 = ((c0 & 1) ? wLo : wHi) +
                       (((size_t)(c0 >> 2) * 128 + y * 64) * 64 + lane) * 8;
  const short* bsrc1 = ((c1 & 1) ? wLo : wHi) +
                       (((size_t)(c1 >> 2) * 128 + y * 64) * 64 + lane) * 8;
  const int bcl0 = (c0 >> 1) & 1, bcl1 = (c1 >> 1) & 1;

  f32x16 acc0 = {}, acc1 = {};
  const int arow = rg * 32 + fr;
  const int r7 = arow & 7;

  short8 cA;                           // constant A operand for MODE 2
  #pragma unroll
  for (int e = 0; e < 8; ++e) cA[e] = (short)(lane * 8 + e);

  #define STAGE(buf, s)                                                         \
    {                                                                           \
      if (useA) {                                                               \
        GLL16(asrc0 + (s) * 32, lbuf[buf] + wave * 2048);                       \
        GLL16(asrc1 + (s) * 32, lbuf[buf] + wave * 2048 + 1024);                \
      }                                                                         \
      if (useB) {                                                               \
        GLL16(bsrc0 + ((s) * 2 + bcl0) * 512, lbuf[buf] + 16384 + c0 * 1024);   \
        GLL16(bsrc1 + ((s) * 2 + bcl1) * 512, lbuf[buf] + 16384 + c1 * 1024);   \
      }                                                                         \
    }

  #pragma unroll 1
  for (int rep = 0; rep < REP; ++rep) {
    STAGE(0, 0);
    STAGE(1, 1);
    #pragma unroll 1
    for (int step = 0; step < NSTEP; ++step) {
      const int buf = step & 1;
      if (step != NSTEP - 1) {
        if (useA && useB) { asm volatile("s_waitcnt vmcnt(4)" ::: "memory"); }
        else              { asm volatile("s_waitcnt vmcnt(2)" ::: "memory"); }
      } else {
        asm volatile("s_waitcnt vmcnt(0)" ::: "memory");
      }
      SBAR; SCHEDB;

      const float* Arow = (const float*)(lbuf[buf]) + arow * 32;
      const short8* Bb  = (const short8*)(lbuf[buf] + 16384);
      float4 a00 = {}, a01 = {}, a10 = {}, a11 = {};
      if (useA) {
        a00 = *(const float4*)(Arow + (((0 + ks * 2 + 0) ^ r7) << 2));
        a01 = *(const float4*)(Arow + (((0 + ks * 2 + 1) ^ r7) << 2));
        a10 = *(const float4*)(Arow + (((4 + ks * 2 + 0) ^ r7) << 2));
        a11 = *(const float4*)(Arow + (((4 + ks * 2 + 1) ^ r7) << 2));
      }
      short8 b000 = cA, b001 = cA, b010 = cA, b011 = cA;
      short8 b100 = cA, b101 = cA, b110 = cA, b111 = cA;
      if (useB) {
        b000 = Bb[((cg * 2 + 0) * 4 + 0 * 2 + 0) * 64 + lane];
        b001 = Bb[((cg * 2 + 0) * 4 + 0 * 2 + 1) * 64 + lane];
        b010 = Bb[((cg * 2 + 1) * 4 + 0 * 2 + 0) * 64 + lane];
        b011 = Bb[((cg * 2 + 1) * 4 + 0 * 2 + 1) * 64 + lane];
        b100 = Bb[((cg * 2 + 0) * 4 + 1 * 2 + 0) * 64 + lane];
        b101 = Bb[((cg * 2 + 0) * 4 + 1 * 2 + 1) * 64 + lane];
        b110 = Bb[((cg * 2 + 1) * 4 + 1 * 2 + 0) * 64 + lane];
        b111 = Bb[((cg * 2 + 1) * 4 + 1 * 2 + 1) * 64 + lane];
      }
      asm volatile("s_waitcnt lgkmcnt(0)" ::: "memory");
      SCHEDB;
      SBAR; SCHEDB;

      if (step + 2 < NSTEP) STAGE(buf, step + 2);

      if (doMM) {
        short8 ah0, al0, ah1, al1;
        if (useA) {
          const float av0[8] = {a00.x, a00.y, a00.z, a00.w, a01.x, a01.y, a01.z, a01.w};
          cvt8(av0, ah0, al0);
          const float av1[8] = {a10.x, a10.y, a10.z, a10.w, a11.x, a11.y, a11.z, a11.w};
          cvt8(av1, ah1, al1);
        } else {
          ah0 = cA; al0 = cA; ah1 = cA; al1 = cA;
        }
        const short8 B00 = useB ? b000 : ah0;
        const short8 B01 = useB ? b001 : al0;
        const short8 B10 = useB ? b010 : ah0;
        const short8 B11 = useB ? b011 : al0;
        const short8 B20 = useB ? b100 : ah1;
        const short8 B21 = useB ? b101 : al1;
        const short8 B30 = useB ? b110 : ah1;
        const short8 B31 = useB ? b111 : al1;
        acc0 = __builtin_amdgcn_mfma_f32_32x32x16_bf16(ah0, B00, acc0, 0, 0, 0);
        acc0 = __builtin_amdgcn_mfma_f32_32x32x16_bf16(ah0, B01, acc0, 0, 0, 0);
        acc0 = __builtin_amdgcn_mfma_f32_32x32x16_bf16(al0, B00, acc0, 0, 0, 0);
        acc1 = __builtin_amdgcn_mfma_f32_32x32x16_bf16(ah0, B10, acc1, 0, 0, 0);
        acc1 = __builtin_amdgcn_mfma_f32_32x32x16_bf16(ah0, B11, acc1, 0, 0, 0);
        acc1 = __builtin_amdgcn_mfma_f32_32x32x16_bf16(al0, B10, acc1, 0, 0, 0);
        acc0 = __builtin_amdgcn_mfma_f32_32x32x16_bf16(ah1, B20, acc0, 0, 0, 0);
        acc0 = __builtin_amdgcn_mfma_f32_32x32x16_bf16(ah1, B21, acc0, 0, 0, 0);
        acc0 = __builtin_amdgcn_mfma_f32_32x32x16_bf16(al1, B20, acc0, 0, 0, 0);
        acc1 = __builtin_amdgcn_mfma_f32_32x32x16_bf16(ah1, B30, acc1, 0, 0, 0);
        acc1 = __builtin_amdgcn_mfma_f32_32x32x16_bf16(ah1, B31, acc1, 0, 0, 0);
        acc1 = __builtin_amdgcn_mfma_f32_32x32x16_bf16(al1, B30, acc1, 0, 0, 0);
      } else {
        // MODE 3: keep A ds_reads live, no MFMA/cvt
        acc0[0] += a00.x + a01.x;
        acc0[1] += a00.y + a01.y;
        acc0[2] += a10.x + a11.x;
        acc0[3] += a10.y + a11.y;
      }
    }
  }
  #undef STAGE

  // epilogue: store fp32 partials (production: MODE 0 REP 1 feeds k1c_pack)
  float* hp = hPart + (size_t)y * ROWS * DSP;
  #pragma unroll
  for (int reg = 0; reg < 16; ++reg) {
    const int row = (reg & 3) + 8 * (reg >> 2) + 4 * ks;
    const size_t base = (size_t)(m0 + rg * 32 + row) * DSP + cg * 64;
    hp[base + fr]      = acc0[reg];
    hp[base + 32 + fr] = acc1[reg];
  }
}

// ---------------- K1c: sum K-halves + bias, split to bf16 hi/lo, pack ----------
__global__ __launch_bounds__(256) void k1c_pack(const float* __restrict__ hPart,
                                                const float* __restrict__ bias,
                                                short* __restrict__ hHi,
                                                short* __restrict__ hLo) {
  const int gid = blockIdx.x * 256 + threadIdx.x;   // 262144 tasks
  const int row = gid >> 4, kc8 = gid & 15;
  const float* p0 = hPart + (size_t)row * 128 + kc8 * 8;
  const float* p1 = p0 + (size_t)ROWS * 128;
  const float4 a0 = *(const float4*)p0, a1 = *(const float4*)(p0 + 4);
  const float4 b0 = *(const float4*)p1, b1 = *(const float4*)(p1 + 4);
  const float4 c0 = *(const float4*)&bias[kc8 * 8];
  const float4 c1 = *(const float4*)&bias[kc8 * 8 + 4];
  const float v[8] = {a0.x + b0.x + c0.x, a0.y + b0.y + c0.y,
                      a0.z + b0.z + c0.z, a0.w + b0.w + c0.w,
                      a1.x + b1.x + c1.x, a1.y + b1.y + c1.y,
                      a1.z + b1.z + c1.z, a1.w + b1.w + c1.w};
  short8 hi8, lo8;
  cvt8(v, hi8, lo8);
  const int kc = kc8 >> 1, kh = kc8 & 1;
  const size_t idx = (size_t)(row >> 5) * 512 + kc * 64 + ((row & 31) + 32 * kh);
  ((short8*)hHi)[idx] = hi8;
  ((short8*)hLo)[idx] = lo8;
}

// ---------------- K2: logits via MFMA + softmax + weighted col-sum -------------
__global__ __launch_bounds__(512, 2) void k2_mfma(const short* __restrict__ hHi,
                                                  const short* __restrict__ hLo,
                                                  const short* __restrict__ eHi,
                                                  const short* __restrict__ eLo,
                                                  const float* __restrict__ imp,
                                                  float* __restrict__ partials) {
  const int t = threadIdx.x;
  const int m0 = blockIdx.x * 64;
  const int seg = blockIdx.y;
  const int wave = t >> 6, lane = t & 63;
  const int wr = wave >> 2;
  const int wc = wave & 3;
  const int fr = lane & 31;
  const int hi = lane >> 5;

  __shared__ float redA[2][32][4];
  __shared__ float redB[2][32][4];
  __shared__ float ldsD[2][512];

  f32x16 acc[4] = {};

  const short8* pAh = (const short8*)hHi + ((m0 >> 5) + wr) * 512 + lane;
  const short8* pAl = (const short8*)hLo + ((m0 >> 5) + wr) * 512 + lane;
  const short8* pBh = (const short8*)eHi + (seg * 16 + wc * 4) * 512 + lane;
  const short8* pBl = (const short8*)eLo + (seg * 16 + wc * 4) * 512 + lane;

  #pragma unroll
  for (int kc = 0; kc < 8; ++kc) {
    const short8 ah = pAh[kc * 64];
    const short8 al = pAl[kc * 64];
    #pragma unroll
    for (int t2 = 0; t2 < 4; ++t2) {
      const short8 bh = pBh[t2 * 512 + kc * 64];
      const short8 bl = pBl[t2 * 512 + kc * 64];
      acc[t2] = __builtin_amdgcn_mfma_f32_32x32x16_bf16(ah, bh, acc[t2], 0, 0, 0);
      acc[t2] = __builtin_amdgcn_mfma_f32_32x32x16_bf16(ah, bl, acc[t2], 0, 0, 0);
      acc[t2] = __builtin_amdgcn_mfma_f32_32x32x16_bf16(al, bh, acc[t2], 0, 0, 0);
    }
  }

  float mx[16];
  #pragma unroll
  for (int r = 0; r < 16; ++r) {
    float m = fmaxf(fmaxf(acc[0][r], acc[1][r]), fmaxf(acc[2][r], acc[3][r]));
    #pragma unroll
    for (int k = 1; k < 32; k <<= 1) m = fmaxf(m, __shfl_xor(m, k));
    mx[r] = m;
  }
  if (fr == 0) {
    #pragma unroll
    for (int r = 0; r < 16; ++r)
      redA[wr][(r & 3) + 8 * (r >> 2) + 4 * hi][wc] = mx[r];
  }
  __syncthreads();
  float M[16];
  #pragma unroll
  for (int r = 0; r < 16; ++r) {
    const int row = (r & 3) + 8 * (r >> 2) + 4 * hi;
    M[r] = fmaxf(fmaxf(redA[wr][row][0], redA[wr][row][1]),
                 fmaxf(redA[wr][row][2], redA[wr][row][3]));
  }

  float sm[16];
  #pragma unroll
  for (int r = 0; r < 16; ++r) {
    float s = 0.0f;
    #pragma unroll
    for (int t2 = 0; t2 < 4; ++t2) {
      const float p = __expf(acc[t2][r] - M[r]);
      acc[t2][r] = p;
      s += p;
    }
    #pragma unroll
    for (int k = 1; k < 32; k <<= 1) s += __shfl_xor(s, k);
    sm[r] = s;
  }
  if (fr == 0) {
    #pragma unroll
    for (int r = 0; r < 16; ++r)
      redB[wr][(r & 3) + 8 * (r >> 2) + 4 * hi][wc] = sm[r];
  }
  __syncthreads();
  float w[16];
  #pragma unroll
  for (int r = 0; r < 16; ++r) {
    const int row = (r & 3) + 8 * (r >> 2) + 4 * hi;
    const float S = (redB[wr][row][0] + redB[wr][row][1]) +
                    (redB[wr][row][2] + redB[wr][row][3]);
    w[r] = imp[m0 + wr * 32 + row] / S;
  }

  #pragma unroll
  for (int t2 = 0; t2 < 4; ++t2) {
    float d = 0.0f;
    #pragma unroll
    for (int r = 0; r < 16; ++r) d = fmaf(acc[t2][r], w[r], d);
    d += __shfl_xor(d, 32);
    if (hi == 0) ldsD[wr][wc * 128 + t2 * 32 + fr] = d;
  }
  __syncthreads();
  partials[((size_t)seg * 256 + blockIdx.x) * 512 + t] = ldsD[0][t] + ldsD[1][t];
}

// ---------------- K3: sum partials (fixed order) + top-k + write ---------------
__global__ __launch_bounds__(256) void k3_topk(const float* __restrict__ partials,
                                               float* __restrict__ out) {
  const int b = blockIdx.x;
  const int seg = blockIdx.y;
  const int tid = threadIdx.x;
  const int K = (seg == 0) ? 8 : ((seg == 1) ? 4 : 6);

  __shared__ float v[512];
  __shared__ float wv[8];
  __shared__ int wi[8];
  __shared__ float redv[4];
  __shared__ int redi[4];

  const float* src = partials + ((size_t)seg * 256 + b * 64) * 512;
  float a0 = 0.f, a1 = 0.f, a2 = 0.f, a3 = 0.f;
  float b0 = 0.f, b1 = 0.f, b2 = 0.f, b3 = 0.f;
  for (int j = 0; j < 64; j += 4) {
    a0 += src[(size_t)(j + 0) * 512 + tid];
    a1 += src[(size_t)(j + 1) * 512 + tid];
    a2 += src[(size_t)(j + 2) * 512 + tid];
    a3 += src[(size_t)(j + 3) * 512 + tid];
    b0 += src[(size_t)(j + 0) * 512 + tid + 256];
    b1 += src[(size_t)(j + 1) * 512 + tid + 256];
    b2 += src[(size_t)(j + 2) * 512 + tid + 256];
    b3 += src[(size_t)(j + 3) * 512 + tid + 256];
  }
  v[tid] = (a0 + a1) + (a2 + a3);
  v[tid + 256] = (b0 + b1) + (b2 + b3);
  __syncthreads();

  for (int t = 0; t < K; ++t) {
    const float v0 = v[tid], v1 = v[tid + 256];
    float bv; int bi;
    if (v1 > v0) { bv = v1; bi = tid + 256; } else { bv = v0; bi = tid; }
    #pragma unroll
    for (int m = 1; m < 64; m <<= 1) {
      const float ov = __shfl_xor(bv, m);
      const int oi = __shfl_xor(bi, m);
      if (ov > bv || (ov == bv && oi < bi)) { bv = ov; bi = oi; }
    }
    if ((tid & 63) == 0) { redv[tid >> 6] = bv; redi[tid >> 6] = bi; }
    __syncthreads();
    if (tid == 0) {
      float best = redv[0]; int besti = redi[0];
      for (int q = 1; q < 4; ++q)
        if (redv[q] > best || (redv[q] == best && redi[q] < besti)) {
          best = redv[q]; besti = redi[q];
        }
      wv[t] = best; wi[t] = besti;
      v[besti] = -3.0e38f;
    }
    __syncthreads();
  }

  float s = 1e-8f;
  for (int t = 0; t < K; ++t) s += wv[t];

  const int slot0 = (seg == 0) ? 0 : ((seg == 1) ? 1 : 3);
  float* o0 = out + slot0 * (BATCH * NSEG) + b * NSEG;
  o0[tid] = 0.0f; o0[tid + 256] = 0.0f;
  float* o1 = nullptr;
  if (seg == 1) {
    o1 = out + 2 * (BATCH * NSEG) + b * NSEG;
    o1[tid] = 0.0f; o1[tid + 256] = 0.0f;
  }
  __syncthreads();
  if (tid < K) {
    const float val = wv[tid] / s;
    o0[wi[tid]] = val;
    if (seg == 1) o1[wi[tid]] = val;
  }
}

// -------------------------------- launch ---------------------------------------
extern "C" void kernel_launch(void* const* d_in, const int* in_sizes, int n_in,
                              void* d_out, int out_size, void* d_ws, size_t ws_size,
                              hipStream_t stream) {
  (void)in_sizes; (void)n_in; (void)out_size; (void)ws_size;
  const float* x    = (const float*)d_in[0];
  const float* imp  = (const float*)d_in[1];
  const float* W    = (const float*)d_in[2];
  const float* bias = (const float*)d_in[3];
  const float* emb  = (const float*)d_in[4];
  float* out = (float*)d_out;

  // workspace carve: partials f32 | hHi hLo eHi eLo wHi wLo (i16) | hPart f32 x2
  float* partials = (float*)d_ws;                     // 393216 f32
  short* hHi      = (short*)(partials + 393216);      // 2097152 i16
  short* hLo      = hHi + 2097152;
  short* eHi      = hLo + 2097152;                    // 196608 i16
  short* eLo      = eHi + 196608;
  short* wHi      = eLo + 196608;                     // 262144 i16
  short* wLo      = wHi + 262144;
  float* hPart    = (float*)(wLo + 262144);           // 2 x 2097152 f32

  // ---- production pipeline (R8 structure, verified) ----
  k0_prep<<<512 + 1536, 64, 0, stream>>>(W, emb, wHi, wLo, eHi, eLo);
  k1_diag<0, 1><<<dim3(ROWS / 128, 2), 512, 0, stream>>>(x, wHi, wLo, hPart);
  k1c_pack<<<1024, 256, 0, stream>>>(hPart, bias, hHi, hLo);
  k2_mfma<<<dim3(ROWS / 64, 3), 512, 0, stream>>>(hHi, hLo, eHi, eLo, imp, partials);
  k3_topk<<<dim3(BATCH, 3), 256, 0, stream>>>(partials, out);

  // ---- diagnostics (write scratch hPart AFTER k1c consumed it; x8 repeat) ----
  k1_diag<0, 8><<<dim3(ROWS / 128, 2), 512, 0, stream>>>(x, wHi, wLo, hPart); // V0 full
  k1_diag<1, 8><<<dim3(ROWS / 128, 2), 512, 0, stream>>>(x, wHi, wLo, hPart); // V1 noB
  k1_diag<2, 8><<<dim3(ROWS / 128, 2), 512, 0, stream>>>(x, wHi, wLo, hPart); // V2 noA
  k1_diag<3, 8><<<dim3(ROWS / 128, 2), 512, 0, stream>>>(x, wHi, wLo, hPart); // V3 memA
}

// Round 14
// 118.033 us; speedup vs baseline: 7.2001x; 7.2001x over previous
//
#include <hip/hip_runtime.h>
#include <hip/hip_bf16.h>

// Problem constants
#define BATCH 4
#define S_TOT 4096
#define ROWS (BATCH * S_TOT)   // 16384
#define DM 2048
#define DSP 128
#define NSEG 512               // neurons per segment; 3 segments

typedef short short8 __attribute__((ext_vector_type(8)));
typedef float f32x16 __attribute__((ext_vector_type(16)));

// float -> bf16(RNE) bits; also returns the fp32 value of the bf16 for residual
static __device__ inline short f2bf(float v, float& back) {
  unsigned u = __float_as_uint(v);
  unsigned r = u + 0x7FFFu + ((u >> 16) & 1u);
  unsigned short hs = (unsigned short)(r >> 16);
  back = __uint_as_float(((unsigned)hs) << 16);
  return (short)hs;
}

// packed f32x2 -> bf16x2 (hw instr). Lo term is exact residual of hi's value.
static __device__ inline unsigned cvtpk2(float a, float b) {
  unsigned r;
  asm("v_cvt_pk_bf16_f32 %0, %1, %2" : "=v"(r) : "v"(a), "v"(b));
  return r;
}
static __device__ inline void cvt8(const float* v, short8& hi8, short8& lo8) {
  union { short8 s; unsigned u[4]; } H, L;
  #pragma unroll
  for (int w = 0; w < 4; ++w) {
    const float f0 = v[2 * w], f1 = v[2 * w + 1];
    const unsigned u = cvtpk2(f0, f1);
    const float b0 = __uint_as_float(u << 16);
    const float b1 = __uint_as_float(u & 0xffff0000u);
    L.u[w] = cvtpk2(f0 - b0, f1 - b1);
    H.u[w] = u;
  }
  hi8 = H.s; lo8 = L.s;
}

// global_load_lds, 16B per lane: per-lane global src, wave-uniform LDS dst
#define GLL16(gsrc, ldst)                                                       \
  __builtin_amdgcn_global_load_lds(                                             \
      (const __attribute__((address_space(1))) void*)(gsrc),                    \
      (__attribute__((address_space(3))) void*)(ldst), 16, 0, 0)

// Fragment layout for a [R][128-k] matrix, per split:
//   short8 index = rowblk*512 + kchunk*64 + lane,  lane=(row&31)+32*((k>>3)&1)
// For W (B-operand, [128 n][2048 k]): short8 index = (tile*128 + kchunk)*64 + lane,
//   lane=(n&31)+32*((k>>3)&1), tile=n>>5.

// ---------------- K0 fused: W-split pack (blocks 0..511) + emb norm pack -------
__global__ __launch_bounds__(64) void k0_prep(const float* __restrict__ W,
                                              const float* __restrict__ emb,
                                              short* __restrict__ wHi,
                                              short* __restrict__ wLo,
                                              short* __restrict__ eHi,
                                              short* __restrict__ eLo) {
  const int l = threadIdx.x;
  if (blockIdx.x < 512) {
    const int tc = blockIdx.x;
    const int t = tc >> 7, c = tc & 127;
    const int n = t * 32 + (l & 31);
    const int k = c * 16 + (l >> 5) * 8;
    const float4 a0 = *(const float4*)&W[(size_t)n * DM + k];
    const float4 a1 = *(const float4*)&W[(size_t)n * DM + k + 4];
    const float av[8] = {a0.x, a0.y, a0.z, a0.w, a1.x, a1.y, a1.z, a1.w};
    short8 hi8, lo8; float bk;
    #pragma unroll
    for (int e = 0; e < 8; ++e) {
      hi8[e] = f2bf(av[e], bk); lo8[e] = f2bf(av[e] - bk, bk);
    }
    const size_t idx = (size_t)tc * 64 + l;
    ((short8*)wHi)[idx] = hi8;
    ((short8*)wLo)[idx] = lo8;
  } else {
    const int row = blockIdx.x - 512;          // 0..1535
    __shared__ short sh[128], sl[128];
    float2 v = *(const float2*)&emb[row * 128 + l * 2];
    float ss = v.x * v.x + v.y * v.y;
    #pragma unroll
    for (int m = 32; m; m >>= 1) ss += __shfl_xor(ss, m);
    const float inv = 1.0f / fmaxf(sqrtf(ss), 1e-12f);
    float bk;
    const float ox = v.x * inv, oy = v.y * inv;
    sh[2 * l] = f2bf(ox, bk);     sl[2 * l] = f2bf(ox - bk, bk);
    sh[2 * l + 1] = f2bf(oy, bk); sl[2 * l + 1] = f2bf(oy - bk, bk);
    __syncthreads();
    if (l < 32) {
      const int split = l >> 4, kc = (l >> 1) & 7, kh = l & 1;
      const short* src = (split ? sl : sh) + kc * 16 + kh * 8;
      const short8 val = *(const short8*)src;
      const size_t idx = (size_t)(row >> 5) * 4096 + kc * 512 +
                         ((row & 31) + 32 * kh) * 8;
      *(short8*)((split ? eLo : eHi) + idx) = val;
    }
  }
}

// ---------------- K1: h-partial = x @ W^T — monolithic 64KB stage, 3 barriers --
// grid (512 row-tiles of 32, 2 K-halves), 256 thr = 4 waves.
// Per phase P in {0,1}: stage 32 rows x 512 k fp32 (64 KB) via 16 GLL16/wave,
// 1 KB line-coalesced bursts (2 KB/row/phase); ONE sync; then barrier-free
// fully-unrolled compute: wave = col-tile ct (32 cols), all 32 rows, 32 kchunks.
// B from L2-resident packed W, loaded only AFTER the sync (no vmcnt poisoning).
// acc accumulates across phases. Epilogue: direct fp32 store (no reduce).
__global__ __launch_bounds__(256, 2) void k1_mfma(const float* __restrict__ x,
                                                  const short* __restrict__ wHi,
                                                  const short* __restrict__ wLo,
                                                  float* __restrict__ hPart) {
  __shared__ __align__(16) float As[16384];   // 64 KB exactly
  const int t = threadIdx.x;
  const int wave = t >> 6, lane = t & 63;     // wave = col-tile ct
  const int fr = lane & 31, ks = lane >> 5;
  const int m0 = blockIdx.x * 32;
  const int y  = blockIdx.y;                  // K-half
  const int r7 = fr & 7;

  f32x16 acc = {};

  // stage phase P: wave stages rows 8*wave..8*wave+7, 2 chunks of 1 KB each.
  // lane l -> granule l of the chunk; source granule XOR-permuted within
  // 128B lines (srcg = (l&~7)|((l&7)^(r&7))); LDS dest linear.
  #define STAGE(P)                                                              \
    {                                                                           \
      _Pragma("unroll")                                                         \
      for (int j = 0; j < 8; ++j)                                               \
        _Pragma("unroll")                                                       \
        for (int c = 0; c < 2; ++c) {                                           \
          const int r = 8 * wave + j;                                           \
          const int srcg = (lane & ~7) | ((lane & 7) ^ (r & 7));                \
          GLL16(x + (size_t)(m0 + r) * DM + y * 1024 + (P) * 512 + c * 256 +    \
                    srcg * 4,                                                   \
                &As[r * 512 + c * 256]);                                        \
        }                                                                       \
    }

  // compute phase P: 32 kchunks, A from LDS (XOR-read), B from packed W (L2)
  #define COMPUTE(P)                                                            \
    {                                                                           \
      const short8* bhp = (const short8*)wHi +                                  \
          ((size_t)wave * 128 + y * 64 + (P) * 32) * 64 + lane;                 \
      const short8* blp = (const short8*)wLo +                                  \
          ((size_t)wave * 128 + y * 64 + (P) * 32) * 64 + lane;                 \
      _Pragma("unroll")                                                         \
      for (int kk = 0; kk < 32; ++kk) {                                         \
        const int g0 = kk * 4 + ks * 2;                                         \
        const int g0s = (g0 & ~7) | ((g0 & 7) ^ r7);                            \
        const int g1s = ((g0 + 1) & ~7) | (((g0 + 1) & 7) ^ r7);                \
        const float4 a0 = *(const float4*)&As[fr * 512 + g0s * 4];              \
        const float4 a1 = *(const float4*)&As[fr * 512 + g1s * 4];              \
        const float av[8] = {a0.x, a0.y, a0.z, a0.w, a1.x, a1.y, a1.z, a1.w};   \
        short8 ah, al;                                                          \
        cvt8(av, ah, al);                                                       \
        const short8 bh = bhp[kk * 64];                                         \
        const short8 bl = blp[kk * 64];                                         \
        acc = __builtin_amdgcn_mfma_f32_32x32x16_bf16(ah, bh, acc, 0, 0, 0);    \
        acc = __builtin_amdgcn_mfma_f32_32x32x16_bf16(ah, bl, acc, 0, 0, 0);    \
        acc = __builtin_amdgcn_mfma_f32_32x32x16_bf16(al, bh, acc, 0, 0, 0);    \
      }                                                                         \
    }

  STAGE(0);
  __syncthreads();    // drains GLLs (vmcnt 0) -> phase-0 data resident
  COMPUTE(0);
  __syncthreads();    // all reads of phase 0 done -> safe to overwrite
  STAGE(1);
  __syncthreads();
  COMPUTE(1);
  #undef STAGE
  #undef COMPUTE

  // epilogue: direct fp32 partial store (each wave owns its 32x32 tile)
  float* hp = hPart + (size_t)y * ROWS * DSP;
  #pragma unroll
  for (int reg = 0; reg < 16; ++reg) {
    const int row = (reg & 3) + 8 * (reg >> 2) + 4 * ks;
    hp[(size_t)(m0 + row) * DSP + wave * 32 + fr] = acc[reg];
  }
}

// ---------------- K1c: sum K-halves + bias, split to bf16 hi/lo, pack ----------
__global__ __launch_bounds__(256) void k1c_pack(const float* __restrict__ hPart,
                                                const float* __restrict__ bias,
                                                short* __restrict__ hHi,
                                                short* __restrict__ hLo) {
  const int gid = blockIdx.x * 256 + threadIdx.x;   // 262144 tasks
  const int row = gid >> 4, kc8 = gid & 15;
  const float* p0 = hPart + (size_t)row * 128 + kc8 * 8;
  const float* p1 = p0 + (size_t)ROWS * 128;
  const float4 a0 = *(const float4*)p0, a1 = *(const float4*)(p0 + 4);
  const float4 b0 = *(const float4*)p1, b1 = *(const float4*)(p1 + 4);
  const float4 c0 = *(const float4*)&bias[kc8 * 8];
  const float4 c1 = *(const float4*)&bias[kc8 * 8 + 4];
  const float v[8] = {a0.x + b0.x + c0.x, a0.y + b0.y + c0.y,
                      a0.z + b0.z + c0.z, a0.w + b0.w + c0.w,
                      a1.x + b1.x + c1.x, a1.y + b1.y + c1.y,
                      a1.z + b1.z + c1.z, a1.w + b1.w + c1.w};
  short8 hi8, lo8;
  cvt8(v, hi8, lo8);
  const int kc = kc8 >> 1, kh = kc8 & 1;
  const size_t idx = (size_t)(row >> 5) * 512 + kc * 64 + ((row & 31) + 32 * kh);
  ((short8*)hHi)[idx] = hi8;
  ((short8*)hLo)[idx] = lo8;
}

// ---------------- K2: logits via MFMA + softmax + weighted col-sum -------------
__global__ __launch_bounds__(512, 2) void k2_mfma(const short* __restrict__ hHi,
                                                  const short* __restrict__ hLo,
                                                  const short* __restrict__ eHi,
                                                  const short* __restrict__ eLo,
                                                  const float* __restrict__ imp,
                                                  float* __restrict__ partials) {
  const int t = threadIdx.x;
  const int m0 = blockIdx.x * 64;
  const int seg = blockIdx.y;
  const int wave = t >> 6, lane = t & 63;
  const int wr = wave >> 2;
  const int wc = wave & 3;
  const int fr = lane & 31;
  const int hi = lane >> 5;

  __shared__ float redA[2][32][4];
  __shared__ float redB[2][32][4];
  __shared__ float ldsD[2][512];

  f32x16 acc[4] = {};

  const short8* pAh = (const short8*)hHi + ((m0 >> 5) + wr) * 512 + lane;
  const short8* pAl = (const short8*)hLo + ((m0 >> 5) + wr) * 512 + lane;
  const short8* pBh = (const short8*)eHi + (seg * 16 + wc * 4) * 512 + lane;
  const short8* pBl = (const short8*)eLo + (seg * 16 + wc * 4) * 512 + lane;

  #pragma unroll
  for (int kc = 0; kc < 8; ++kc) {
    const short8 ah = pAh[kc * 64];
    const short8 al = pAl[kc * 64];
    #pragma unroll
    for (int t2 = 0; t2 < 4; ++t2) {
      const short8 bh = pBh[t2 * 512 + kc * 64];
      const short8 bl = pBl[t2 * 512 + kc * 64];
      acc[t2] = __builtin_amdgcn_mfma_f32_32x32x16_bf16(ah, bh, acc[t2], 0, 0, 0);
      acc[t2] = __builtin_amdgcn_mfma_f32_32x32x16_bf16(ah, bl, acc[t2], 0, 0, 0);
      acc[t2] = __builtin_amdgcn_mfma_f32_32x32x16_bf16(al, bh, acc[t2], 0, 0, 0);
    }
  }

  float mx[16];
  #pragma unroll
  for (int r = 0; r < 16; ++r) {
    float m = fmaxf(fmaxf(acc[0][r], acc[1][r]), fmaxf(acc[2][r], acc[3][r]));
    #pragma unroll
    for (int k = 1; k < 32; k <<= 1) m = fmaxf(m, __shfl_xor(m, k));
    mx[r] = m;
  }
  if (fr == 0) {
    #pragma unroll
    for (int r = 0; r < 16; ++r)
      redA[wr][(r & 3) + 8 * (r >> 2) + 4 * hi][wc] = mx[r];
  }
  __syncthreads();
  float M[16];
  #pragma unroll
  for (int r = 0; r < 16; ++r) {
    const int row = (r & 3) + 8 * (r >> 2) + 4 * hi;
    M[r] = fmaxf(fmaxf(redA[wr][row][0], redA[wr][row][1]),
                 fmaxf(redA[wr][row][2], redA[wr][row][3]));
  }

  float sm[16];
  #pragma unroll
  for (int r = 0; r < 16; ++r) {
    float s = 0.0f;
    #pragma unroll
    for (int t2 = 0; t2 < 4; ++t2) {
      const float p = __expf(acc[t2][r] - M[r]);
      acc[t2][r] = p;
      s += p;
    }
    #pragma unroll
    for (int k = 1; k < 32; k <<= 1) s += __shfl_xor(s, k);
    sm[r] = s;
  }
  if (fr == 0) {
    #pragma unroll
    for (int r = 0; r < 16; ++r)
      redB[wr][(r & 3) + 8 * (r >> 2) + 4 * hi][wc] = sm[r];
  }
  __syncthreads();
  float w[16];
  #pragma unroll
  for (int r = 0; r < 16; ++r) {
    const int row = (r & 3) + 8 * (r >> 2) + 4 * hi;
    const float S = (redB[wr][row][0] + redB[wr][row][1]) +
                    (redB[wr][row][2] + redB[wr][row][3]);
    w[r] = imp[m0 + wr * 32 + row] / S;
  }

  #pragma unroll
  for (int t2 = 0; t2 < 4; ++t2) {
    float d = 0.0f;
    #pragma unroll
    for (int r = 0; r < 16; ++r) d = fmaf(acc[t2][r], w[r], d);
    d += __shfl_xor(d, 32);
    if (hi == 0) ldsD[wr][wc * 128 + t2 * 32 + fr] = d;
  }
  __syncthreads();
  partials[((size_t)seg * 256 + blockIdx.x) * 512 + t] = ldsD[0][t] + ldsD[1][t];
}

// ---------------- K3: sum partials (fixed order) + top-k + write ---------------
__global__ __launch_bounds__(256) void k3_topk(const float* __restrict__ partials,
                                               float* __restrict__ out) {
  const int b = blockIdx.x;
  const int seg = blockIdx.y;
  const int tid = threadIdx.x;
  const int K = (seg == 0) ? 8 : ((seg == 1) ? 4 : 6);

  __shared__ float v[512];
  __shared__ float wv[8];
  __shared__ int wi[8];
  __shared__ float redv[4];
  __shared__ int redi[4];

  const float* src = partials + ((size_t)seg * 256 + b * 64) * 512;
  float a0 = 0.f, a1 = 0.f, a2 = 0.f, a3 = 0.f;
  float b0 = 0.f, b1 = 0.f, b2 = 0.f, b3 = 0.f;
  for (int j = 0; j < 64; j += 4) {
    a0 += src[(size_t)(j + 0) * 512 + tid];
    a1 += src[(size_t)(j + 1) * 512 + tid];
    a2 += src[(size_t)(j + 2) * 512 + tid];
    a3 += src[(size_t)(j + 3) * 512 + tid];
    b0 += src[(size_t)(j + 0) * 512 + tid + 256];
    b1 += src[(size_t)(j + 1) * 512 + tid + 256];
    b2 += src[(size_t)(j + 2) * 512 + tid + 256];
    b3 += src[(size_t)(j + 3) * 512 + tid + 256];
  }
  v[tid] = (a0 + a1) + (a2 + a3);
  v[tid + 256] = (b0 + b1) + (b2 + b3);
  __syncthreads();

  for (int t = 0; t < K; ++t) {
    const float v0 = v[tid], v1 = v[tid + 256];
    float bv; int bi;
    if (v1 > v0) { bv = v1; bi = tid + 256; } else { bv = v0; bi = tid; }
    #pragma unroll
    for (int m = 1; m < 64; m <<= 1) {
      const float ov = __shfl_xor(bv, m);
      const int oi = __shfl_xor(bi, m);
      if (ov > bv || (ov == bv && oi < bi)) { bv = ov; bi = oi; }
    }
    if ((tid & 63) == 0) { redv[tid >> 6] = bv; redi[tid >> 6] = bi; }
    __syncthreads();
    if (tid == 0) {
      float best = redv[0]; int besti = redi[0];
      for (int q = 1; q < 4; ++q)
        if (redv[q] > best || (redv[q] == best && redi[q] < besti)) {
          best = redv[q]; besti = redi[q];
        }
      wv[t] = best; wi[t] = besti;
      v[besti] = -3.0e38f;
    }
    __syncthreads();
  }

  float s = 1e-8f;
  for (int t = 0; t < K; ++t) s += wv[t];

  const int slot0 = (seg == 0) ? 0 : ((seg == 1) ? 1 : 3);
  float* o0 = out + slot0 * (BATCH * NSEG) + b * NSEG;
  o0[tid] = 0.0f; o0[tid + 256] = 0.0f;
  float* o1 = nullptr;
  if (seg == 1) {
    o1 = out + 2 * (BATCH * NSEG) + b * NSEG;
    o1[tid] = 0.0f; o1[tid + 256] = 0.0f;
  }
  __syncthreads();
  if (tid < K) {
    const float val = wv[tid] / s;
    o0[wi[tid]] = val;
    if (seg == 1) o1[wi[tid]] = val;
  }
}

// -------------------------------- launch ---------------------------------------
extern "C" void kernel_launch(void* const* d_in, const int* in_sizes, int n_in,
                              void* d_out, int out_size, void* d_ws, size_t ws_size,
                              hipStream_t stream) {
  (void)in_sizes; (void)n_in; (void)out_size; (void)ws_size;
  const float* x    = (const float*)d_in[0];
  const float* imp  = (const float*)d_in[1];
  const float* W    = (const float*)d_in[2];
  const float* bias = (const float*)d_in[3];
  const float* emb  = (const float*)d_in[4];
  float* out = (float*)d_out;

  // workspace carve: partials f32 | hHi hLo eHi eLo wHi wLo (i16) | hPart f32 x2
  float* partials = (float*)d_ws;                     // 393216 f32
  short* hHi      = (short*)(partials + 393216);      // 2097152 i16
  short* hLo      = hHi + 2097152;
  short* eHi      = hLo + 2097152;                    // 196608 i16
  short* eLo      = eHi + 196608;
  short* wHi      = eLo + 196608;                     // 262144 i16
  short* wLo      = wHi + 262144;
  float* hPart    = (float*)(wLo + 262144);           // 2 x 2097152 f32

  k0_prep<<<512 + 1536, 64, 0, stream>>>(W, emb, wHi, wLo, eHi, eLo);
  k1_mfma<<<dim3(ROWS / 32, 2), 256, 0, stream>>>(x, wHi, wLo, hPart);
  k1c_pack<<<1024, 256, 0, stream>>>(hPart, bias, hHi, hLo);
  k2_mfma<<<dim3(ROWS / 64, 3), 512, 0, stream>>>(hHi, hLo, eHi, eLo, imp, partials);
  k3_topk<<<dim3(BATCH, 3), 256, 0, stream>>>(partials, out);
}

// Round 15
// 109.865 us; speedup vs baseline: 7.7354x; 1.0743x over previous
//
#include <hip/hip_runtime.h>
#include <hip/hip_bf16.h>

// Problem constants
#define BATCH 4
#define S_TOT 4096
#define ROWS (BATCH * S_TOT)   // 16384
#define DM 2048
#define DSP 128
#define NSEG 512               // neurons per segment; 3 segments

typedef short short8 __attribute__((ext_vector_type(8)));
typedef float f32x16 __attribute__((ext_vector_type(16)));

// float -> bf16(RNE) bits; also returns the fp32 value of the bf16 for residual
static __device__ inline short f2bf(float v, float& back) {
  unsigned u = __float_as_uint(v);
  unsigned r = u + 0x7FFFu + ((u >> 16) & 1u);
  unsigned short hs = (unsigned short)(r >> 16);
  back = __uint_as_float(((unsigned)hs) << 16);
  return (short)hs;
}

// packed f32x2 -> bf16x2 (hw instr). Lo term is exact residual of hi's value.
static __device__ inline unsigned cvtpk2(float a, float b) {
  unsigned r;
  asm("v_cvt_pk_bf16_f32 %0, %1, %2" : "=v"(r) : "v"(a), "v"(b));
  return r;
}
static __device__ inline void cvt8(const float* v, short8& hi8, short8& lo8) {
  union { short8 s; unsigned u[4]; } H, L;
  #pragma unroll
  for (int w = 0; w < 4; ++w) {
    const float f0 = v[2 * w], f1 = v[2 * w + 1];
    const unsigned u = cvtpk2(f0, f1);
    const float b0 = __uint_as_float(u << 16);
    const float b1 = __uint_as_float(u & 0xffff0000u);
    L.u[w] = cvtpk2(f0 - b0, f1 - b1);
    H.u[w] = u;
  }
  hi8 = H.s; lo8 = L.s;
}

// global_load_lds, 16B per lane: per-lane global src, wave-uniform LDS dst
#define GLL16(gsrc, ldst)                                                       \
  __builtin_amdgcn_global_load_lds(                                             \
      (const __attribute__((address_space(1))) void*)(gsrc),                    \
      (__attribute__((address_space(3))) void*)(ldst), 16, 0, 0)

#define SBAR   __builtin_amdgcn_s_barrier()
#define SCHEDB __builtin_amdgcn_sched_barrier(0)

// Fragment layout for a [R][128-k] matrix, per split:
//   short8 index = rowblk*512 + kchunk*64 + lane,  lane=(row&31)+32*((k>>3)&1)
// For W (B-operand, [128 n][2048 k]): short8 index = (tile*128 + kchunk)*64 + lane,
//   lane=(n&31)+32*((k>>3)&1), tile=n>>5.

// ---------------- K0 fused: W-split pack (blocks 0..511) + emb norm pack -------
__global__ __launch_bounds__(64) void k0_prep(const float* __restrict__ W,
                                              const float* __restrict__ emb,
                                              short* __restrict__ wHi,
                                              short* __restrict__ wLo,
                                              short* __restrict__ eHi,
                                              short* __restrict__ eLo) {
  const int l = threadIdx.x;
  if (blockIdx.x < 512) {
    const int tc = blockIdx.x;
    const int t = tc >> 7, c = tc & 127;
    const int n = t * 32 + (l & 31);
    const int k = c * 16 + (l >> 5) * 8;
    const float4 a0 = *(const float4*)&W[(size_t)n * DM + k];
    const float4 a1 = *(const float4*)&W[(size_t)n * DM + k + 4];
    const float av[8] = {a0.x, a0.y, a0.z, a0.w, a1.x, a1.y, a1.z, a1.w};
    short8 hi8, lo8; float bk;
    #pragma unroll
    for (int e = 0; e < 8; ++e) {
      hi8[e] = f2bf(av[e], bk); lo8[e] = f2bf(av[e] - bk, bk);
    }
    const size_t idx = (size_t)tc * 64 + l;
    ((short8*)wHi)[idx] = hi8;
    ((short8*)wLo)[idx] = lo8;
  } else {
    const int row = blockIdx.x - 512;          // 0..1535
    __shared__ short sh[128], sl[128];
    float2 v = *(const float2*)&emb[row * 128 + l * 2];
    float ss = v.x * v.x + v.y * v.y;
    #pragma unroll
    for (int m = 32; m; m >>= 1) ss += __shfl_xor(ss, m);
    const float inv = 1.0f / fmaxf(sqrtf(ss), 1e-12f);
    float bk;
    const float ox = v.x * inv, oy = v.y * inv;
    sh[2 * l] = f2bf(ox, bk);     sl[2 * l] = f2bf(ox - bk, bk);
    sh[2 * l + 1] = f2bf(oy, bk); sl[2 * l + 1] = f2bf(oy - bk, bk);
    __syncthreads();
    if (l < 32) {
      const int split = l >> 4, kc = (l >> 1) & 7, kh = l & 1;
      const short* src = (split ? sl : sh) + kc * 16 + kh * 8;
      const short8 val = *(const short8*)src;
      const size_t idx = (size_t)(row >> 5) * 4096 + kc * 512 +
                         ((row & 31) + 32 * kh) * 8;
      *(short8*)((split ? eLo : eHi) + idx) = val;
    }
  }
}

// ---------------- K1: h-half = x @ W^T — R8 counted-vmcnt loop, BM=64 ----------
// grid (256 row-tiles of 64, 2 K-halves), 512 thr = 8 waves = 2 rg x 4 cg.
// Per step (BK=32), per wave: 1 A GLL16 + 2 B GLL16; vmcnt(3)->barrier->
// 8 ds_read_b128 -> lgkmcnt(0) -> barrier -> stage(s+2) -> cvt + 6 MFMA.
// Epilogue: acc->LDS + bias (y==0 only) + bf16-split pack per half (k1c dead).
#define NSTEP 32
__global__ __launch_bounds__(512, 2) void k1_mfma(const float* __restrict__ x,
                                                  const short* __restrict__ wHi,
                                                  const short* __restrict__ wLo,
                                                  const float* __restrict__ bias,
                                                  short* __restrict__ hH0,
                                                  short* __restrict__ hL0,
                                                  short* __restrict__ hH1,
                                                  short* __restrict__ hL1) {
  __shared__ __align__(16) union {
    char lbuf[2][24576];                      // per buf: A 8KB | B 16KB
    struct { float hsum[64][132]; float bsh[128]; } ep;
  } sm;                                       // 48 KB
  const int t = threadIdx.x;
  const int wave = t >> 6, lane = t & 63;
  const int fr = lane & 31, ks = lane >> 5;
  const int rg = wave >> 2, cg = wave & 3;    // rows rg*32, cols cg*32
  const int m0 = blockIdx.x * 64;
  const int y  = blockIdx.y;                  // K-half

  // A staging: wave stages rows wave*8..+7, 128B (32 floats) per row per step.
  // lane l -> row wave*8+(l>>3), dst granule l&7; src granule (l&7)^(row&7).
  const int arow_s = wave * 8 + (lane >> 3);
  const float* asrc = x + (size_t)(m0 + arow_s) * DM + y * 1024 +
                      (((lane & 7) ^ (arow_s & 7)) << 2);
  // B staging: combo c = tile*4 + kcsel*2 + sp; wave owns c0 = 2*wave, c1 = +1.
  const int c0 = wave * 2, c1 = wave * 2 + 1;
  const short* bsrc0 = ((c0 & 1) ? wLo : wHi) +
                       (((size_t)(c0 >> 2) * 128 + y * 64) * 64 + lane) * 8;
  const short* bsrc1 = ((c1 & 1) ? wLo : wHi) +
                       (((size_t)(c1 >> 2) * 128 + y * 64) * 64 + lane) * 8;
  const int kc0 = (c0 >> 1) & 1, kc1 = (c1 >> 1) & 1;

  #define STAGE(buf, s)                                                         \
    {                                                                           \
      GLL16(asrc + (s) * 32, sm.lbuf[buf] + wave * 1024);                       \
      GLL16(bsrc0 + ((s) * 2 + kc0) * 512, sm.lbuf[buf] + 8192 + c0 * 1024);    \
      GLL16(bsrc1 + ((s) * 2 + kc1) * 512, sm.lbuf[buf] + 8192 + c1 * 1024);    \
    }

  f32x16 acc = {};
  const int arow = rg * 32 + fr;
  const int r7 = arow & 7;

  STAGE(0, 0);
  STAGE(1, 1);

  #pragma unroll 1
  for (int s = 0; s < NSTEP; ++s) {
    const int buf = s & 1;
    if (s != NSTEP - 1) {
      asm volatile("s_waitcnt vmcnt(3)" ::: "memory");   // cur buf done; next in flight
    } else {
      asm volatile("s_waitcnt vmcnt(0)" ::: "memory");
    }
    SBAR; SCHEDB;

    const float* Ar = (const float*)(sm.lbuf[buf]) + arow * 32;
    const short8* Bb = (const short8*)(sm.lbuf[buf] + 8192);
    // A: 2 kchunks x 2 granule-pairs (XOR involution read)
    float4 a00 = *(const float4*)(Ar + (((0 * 4 + ks * 2 + 0) ^ r7) << 2));
    float4 a01 = *(const float4*)(Ar + (((0 * 4 + ks * 2 + 1) ^ r7) << 2));
    float4 a10 = *(const float4*)(Ar + (((1 * 4 + ks * 2 + 0) ^ r7) << 2));
    float4 a11 = *(const float4*)(Ar + (((1 * 4 + ks * 2 + 1) ^ r7) << 2));
    // B: combo (tile=cg, kk, sp)
    short8 b00 = Bb[(cg * 4 + 0 * 2 + 0) * 64 + lane];
    short8 b01 = Bb[(cg * 4 + 0 * 2 + 1) * 64 + lane];
    short8 b10 = Bb[(cg * 4 + 1 * 2 + 0) * 64 + lane];
    short8 b11 = Bb[(cg * 4 + 1 * 2 + 1) * 64 + lane];
    asm volatile("s_waitcnt lgkmcnt(0)" ::: "memory");
    SCHEDB;
    SBAR; SCHEDB;      // all waves' reads landed -> safe to overwrite buf

    if (s + 2 < NSTEP) STAGE(buf, s + 2);

    {
      const float av[8] = {a00.x, a00.y, a00.z, a00.w, a01.x, a01.y, a01.z, a01.w};
      short8 ah, al; cvt8(av, ah, al);
      acc = __builtin_amdgcn_mfma_f32_32x32x16_bf16(ah, b00, acc, 0, 0, 0);
      acc = __builtin_amdgcn_mfma_f32_32x32x16_bf16(ah, b01, acc, 0, 0, 0);
      acc = __builtin_amdgcn_mfma_f32_32x32x16_bf16(al, b00, acc, 0, 0, 0);
    }
    {
      const float av[8] = {a10.x, a10.y, a10.z, a10.w, a11.x, a11.y, a11.z, a11.w};
      short8 ah, al; cvt8(av, ah, al);
      acc = __builtin_amdgcn_mfma_f32_32x32x16_bf16(ah, b10, acc, 0, 0, 0);
      acc = __builtin_amdgcn_mfma_f32_32x32x16_bf16(ah, b11, acc, 0, 0, 0);
      acc = __builtin_amdgcn_mfma_f32_32x32x16_bf16(al, b10, acc, 0, 0, 0);
    }
  }
  #undef STAGE

  // ---- epilogue: dump acc, add bias (y==0), bf16-split pack (no k1c) ----
  __syncthreads();                            // lbuf reads fully retired
  if (t < 128) sm.ep.bsh[t] = (y == 0) ? bias[t] : 0.0f;
  #pragma unroll
  for (int reg = 0; reg < 16; ++reg) {
    const int row = (reg & 3) + 8 * (reg >> 2) + 4 * ks;
    sm.ep.hsum[rg * 32 + row][cg * 32 + fr] = acc[reg];
  }
  __syncthreads();
  short* hH = y ? hH1 : hH0;
  short* hL = y ? hL1 : hL0;
  #pragma unroll
  for (int i = 0; i < 2; ++i) {
    const int task = t + 512 * i;             // 1024 tasks: 64 rows x 16 kc8
    const int row = task >> 4, kc8 = task & 15;
    float v[8];
    #pragma unroll
    for (int j = 0; j < 8; ++j)
      v[j] = sm.ep.hsum[row][kc8 * 8 + j] + sm.ep.bsh[kc8 * 8 + j];
    short8 hi8, lo8;
    cvt8(v, hi8, lo8);
    const size_t idx = ((size_t)blockIdx.x * 2 + (row >> 5)) * 512 +
                       (kc8 >> 1) * 64 + ((row & 31) + 32 * (kc8 & 1));
    ((short8*)hH)[idx] = hi8;
    ((short8*)hL)[idx] = lo8;
  }
}

// ---------------- K2: logits from 2 split-pairs + softmax + weighted colsum ----
// grid (256 row-tiles of 64, 3 segments), 512 threads = 8 waves.
// logits = (h0h+h0l+h1h+h1l)·eh + (h0h+h1h)·el  (lo·lo terms dropped, ~2^-18).
// bias is already inside the h0 pair (added in k1 y==0 epilogue).
__global__ __launch_bounds__(512, 2) void k2_mfma(const short* __restrict__ hH0,
                                                  const short* __restrict__ hL0,
                                                  const short* __restrict__ hH1,
                                                  const short* __restrict__ hL1,
                                                  const short* __restrict__ eHi,
                                                  const short* __restrict__ eLo,
                                                  const float* __restrict__ imp,
                                                  float* __restrict__ partials) {
  const int t = threadIdx.x;
  const int m0 = blockIdx.x * 64;
  const int seg = blockIdx.y;
  const int wave = t >> 6, lane = t & 63;
  const int wr = wave >> 2;
  const int wc = wave & 3;
  const int fr = lane & 31;
  const int hi = lane >> 5;

  __shared__ float redA[2][32][4];
  __shared__ float redB[2][32][4];
  __shared__ float ldsD[2][512];

  f32x16 acc[4] = {};

  const size_t abase = (size_t)((m0 >> 5) + wr) * 512 + lane;
  const short8* pA0h = (const short8*)hH0 + abase;
  const short8* pA0l = (const short8*)hL0 + abase;
  const short8* pA1h = (const short8*)hH1 + abase;
  const short8* pA1l = (const short8*)hL1 + abase;
  const short8* pBh = (const short8*)eHi + (seg * 16 + wc * 4) * 512 + lane;
  const short8* pBl = (const short8*)eLo + (seg * 16 + wc * 4) * 512 + lane;

  #pragma unroll
  for (int kc = 0; kc < 8; ++kc) {
    const short8 a0h = pA0h[kc * 64], a0l = pA0l[kc * 64];
    const short8 a1h = pA1h[kc * 64], a1l = pA1l[kc * 64];
    #pragma unroll
    for (int t2 = 0; t2 < 4; ++t2) {
      const short8 bh = pBh[t2 * 512 + kc * 64];
      const short8 bl = pBl[t2 * 512 + kc * 64];
      acc[t2] = __builtin_amdgcn_mfma_f32_32x32x16_bf16(a0h, bh, acc[t2], 0, 0, 0);
      acc[t2] = __builtin_amdgcn_mfma_f32_32x32x16_bf16(a0l, bh, acc[t2], 0, 0, 0);
      acc[t2] = __builtin_amdgcn_mfma_f32_32x32x16_bf16(a1h, bh, acc[t2], 0, 0, 0);
      acc[t2] = __builtin_amdgcn_mfma_f32_32x32x16_bf16(a1l, bh, acc[t2], 0, 0, 0);
      acc[t2] = __builtin_amdgcn_mfma_f32_32x32x16_bf16(a0h, bl, acc[t2], 0, 0, 0);
      acc[t2] = __builtin_amdgcn_mfma_f32_32x32x16_bf16(a1h, bl, acc[t2], 0, 0, 0);
    }
  }

  float mx[16];
  #pragma unroll
  for (int r = 0; r < 16; ++r) {
    float m = fmaxf(fmaxf(acc[0][r], acc[1][r]), fmaxf(acc[2][r], acc[3][r]));
    #pragma unroll
    for (int k = 1; k < 32; k <<= 1) m = fmaxf(m, __shfl_xor(m, k));
    mx[r] = m;
  }
  if (fr == 0) {
    #pragma unroll
    for (int r = 0; r < 16; ++r)
      redA[wr][(r & 3) + 8 * (r >> 2) + 4 * hi][wc] = mx[r];
  }
  __syncthreads();
  float M[16];
  #pragma unroll
  for (int r = 0; r < 16; ++r) {
    const int row = (r & 3) + 8 * (r >> 2) + 4 * hi;
    M[r] = fmaxf(fmaxf(redA[wr][row][0], redA[wr][row][1]),
                 fmaxf(redA[wr][row][2], redA[wr][row][3]));
  }

  float sm[16];
  #pragma unroll
  for (int r = 0; r < 16; ++r) {
    float s = 0.0f;
    #pragma unroll
    for (int t2 = 0; t2 < 4; ++t2) {
      const float p = __expf(acc[t2][r] - M[r]);
      acc[t2][r] = p;
      s += p;
    }
    #pragma unroll
    for (int k = 1; k < 32; k <<= 1) s += __shfl_xor(s, k);
    sm[r] = s;
  }
  if (fr == 0) {
    #pragma unroll
    for (int r = 0; r < 16; ++r)
      redB[wr][(r & 3) + 8 * (r >> 2) + 4 * hi][wc] = sm[r];
  }
  __syncthreads();
  float w[16];
  #pragma unroll
  for (int r = 0; r < 16; ++r) {
    const int row = (r & 3) + 8 * (r >> 2) + 4 * hi;
    const float S = (redB[wr][row][0] + redB[wr][row][1]) +
                    (redB[wr][row][2] + redB[wr][row][3]);
    w[r] = imp[m0 + wr * 32 + row] / S;
  }

  #pragma unroll
  for (int t2 = 0; t2 < 4; ++t2) {
    float d = 0.0f;
    #pragma unroll
    for (int r = 0; r < 16; ++r) d = fmaf(acc[t2][r], w[r], d);
    d += __shfl_xor(d, 32);
    if (hi == 0) ldsD[wr][wc * 128 + t2 * 32 + fr] = d;
  }
  __syncthreads();
  partials[((size_t)seg * 256 + blockIdx.x) * 512 + t] = ldsD[0][t] + ldsD[1][t];
}

// ---------------- K3: sum partials (fixed order) + top-k + write ---------------
__global__ __launch_bounds__(256) void k3_topk(const float* __restrict__ partials,
                                               float* __restrict__ out) {
  const int b = blockIdx.x;
  const int seg = blockIdx.y;
  const int tid = threadIdx.x;
  const int K = (seg == 0) ? 8 : ((seg == 1) ? 4 : 6);

  __shared__ float v[512];
  __shared__ float wv[8];
  __shared__ int wi[8];
  __shared__ float redv[4];
  __shared__ int redi[4];

  const float* src = partials + ((size_t)seg * 256 + b * 64) * 512;
  float a0 = 0.f, a1 = 0.f, a2 = 0.f, a3 = 0.f;
  float b0 = 0.f, b1 = 0.f, b2 = 0.f, b3 = 0.f;
  for (int j = 0; j < 64; j += 4) {
    a0 += src[(size_t)(j + 0) * 512 + tid];
    a1 += src[(size_t)(j + 1) * 512 + tid];
    a2 += src[(size_t)(j + 2) * 512 + tid];
    a3 += src[(size_t)(j + 3) * 512 + tid];
    b0 += src[(size_t)(j + 0) * 512 + tid + 256];
    b1 += src[(size_t)(j + 1) * 512 + tid + 256];
    b2 += src[(size_t)(j + 2) * 512 + tid + 256];
    b3 += src[(size_t)(j + 3) * 512 + tid + 256];
  }
  v[tid] = (a0 + a1) + (a2 + a3);
  v[tid + 256] = (b0 + b1) + (b2 + b3);
  __syncthreads();

  for (int t = 0; t < K; ++t) {
    const float v0 = v[tid], v1 = v[tid + 256];
    float bv; int bi;
    if (v1 > v0) { bv = v1; bi = tid + 256; } else { bv = v0; bi = tid; }
    #pragma unroll
    for (int m = 1; m < 64; m <<= 1) {
      const float ov = __shfl_xor(bv, m);
      const int oi = __shfl_xor(bi, m);
      if (ov > bv || (ov == bv && oi < bi)) { bv = ov; bi = oi; }
    }
    if ((tid & 63) == 0) { redv[tid >> 6] = bv; redi[tid >> 6] = bi; }
    __syncthreads();
    if (tid == 0) {
      float best = redv[0]; int besti = redi[0];
      for (int q = 1; q < 4; ++q)
        if (redv[q] > best || (redv[q] == best && redi[q] < besti)) {
          best = redv[q]; besti = redi[q];
        }
      wv[t] = best; wi[t] = besti;
      v[besti] = -3.0e38f;
    }
    __syncthreads();
  }

  float s = 1e-8f;
  for (int t = 0; t < K; ++t) s += wv[t];

  const int slot0 = (seg == 0) ? 0 : ((seg == 1) ? 1 : 3);
  float* o0 = out + slot0 * (BATCH * NSEG) + b * NSEG;
  o0[tid] = 0.0f; o0[tid + 256] = 0.0f;
  float* o1 = nullptr;
  if (seg == 1) {
    o1 = out + 2 * (BATCH * NSEG) + b * NSEG;
    o1[tid] = 0.0f; o1[tid + 256] = 0.0f;
  }
  __syncthreads();
  if (tid < K) {
    const float val = wv[tid] / s;
    o0[wi[tid]] = val;
    if (seg == 1) o1[wi[tid]] = val;
  }
}

// -------------------------------- launch ---------------------------------------
extern "C" void kernel_launch(void* const* d_in, const int* in_sizes, int n_in,
                              void* d_out, int out_size, void* d_ws, size_t ws_size,
                              hipStream_t stream) {
  (void)in_sizes; (void)n_in; (void)out_size; (void)ws_size;
  const float* x    = (const float*)d_in[0];
  const float* imp  = (const float*)d_in[1];
  const float* W    = (const float*)d_in[2];
  const float* bias = (const float*)d_in[3];
  const float* emb  = (const float*)d_in[4];
  float* out = (float*)d_out;

  // workspace: partials f32 | hH0 hL0 hH1 hL1 | eHi eLo | wHi wLo (i16)
  float* partials = (float*)d_ws;                     // 393216 f32
  short* hH0      = (short*)(partials + 393216);      // 2097152 i16 each
  short* hL0      = hH0 + 2097152;
  short* hH1      = hL0 + 2097152;
  short* hL1      = hH1 + 2097152;
  short* eHi      = hL1 + 2097152;                    // 196608 i16
  short* eLo      = eHi + 196608;
  short* wHi      = eLo + 196608;                     // 262144 i16
  short* wLo      = wHi + 262144;

  k0_prep<<<512 + 1536, 64, 0, stream>>>(W, emb, wHi, wLo, eHi, eLo);
  k1_mfma<<<dim3(ROWS / 64, 2), 512, 0, stream>>>(x, wHi, wLo, bias,
                                                  hH0, hL0, hH1, hL1);
  k2_mfma<<<dim3(ROWS / 64, 3), 512, 0, stream>>>(hH0, hL0, hH1, hL1,
                                                  eHi, eLo, imp, partials);
  k3_topk<<<dim3(BATCH, 3), 256, 0, stream>>>(partials, out);
}